// Round 8
// baseline (366.034 us; speedup 1.0000x reference)
//
#include <hip/hip_runtime.h>
#include <stdint.h>

// ---------------------------------------------------------------------------
// DualGatedRecurrence on MI355X.
// fwht() in the reference is the identity for D=1024 (butterfly S: S^2=2I;
// 10 steps = 32*I, cancelled by d^-0.5) => hproj(x,s) = x * prod_i(s_i).
// Pipeline (3 dispatches, NO cooperative launch — R7 showed it breaks graph
// capture):
//   k_scan: block = 1024 thr = 64 chunks x 16 d-pairs — one block owns a
//     full (b, 32-channel) sequence, so the chunk-carry combine is a
//     __syncthreads/LDS problem (no grid sync, no P/H global traffic).
//     preload-all x into regs -> local scan -> P/H to LDS -> barrier ->
//     in-LDS carry prefix -> rescan FROM REGISTERS -> hcat (f32-exact).
//     Prep (weights->bf16, rowsum zero) rides along as extra blocks.
//   GEMM1: 16x16x32 bf16 MFMA, BK=64, XOR-swizzled LDS (conflict-free,
//     verified R3+), XCD-aware remap (verified R4: FETCH 86->44 MB);
//     epilogue sigmoid*hcat + fused row sum-of-squares atomics.
//   GEMM2: same structure, rsqrt row-scale epilogue.
// ---------------------------------------------------------------------------

typedef __attribute__((ext_vector_type(8))) short short8;     // 8 bf16
typedef __attribute__((ext_vector_type(4))) float f32x4;
typedef __attribute__((ext_vector_type(2))) float f32x2;
typedef __attribute__((ext_vector_type(4))) unsigned short ushort4v;
typedef __attribute__((ext_vector_type(2))) unsigned short ushort2v;

typedef const __attribute__((address_space(1))) unsigned int* as1_u32p;
typedef __attribute__((address_space(3))) unsigned int* as3_u32p;

__device__ __forceinline__ void cp16(const void* g, void* l) {
  __builtin_amdgcn_global_load_lds((as1_u32p)(uintptr_t)g,
                                   (as3_u32p)(unsigned int)(uintptr_t)l,
                                   16, 0, 0);
}

__device__ __forceinline__ float b2f(unsigned short h) {
  union { unsigned int u; float f; } v; v.u = ((unsigned int)h) << 16; return v.f;
}
__device__ __forceinline__ unsigned short f2b(float f) {
  union { float f; unsigned int u; } v; v.f = f;
  unsigned int r = v.u + 0x7fffu + ((v.u >> 16) & 1u);   // round-nearest-even
  return (unsigned short)(r >> 16);
}
// fast sigmoid: hw exp + hw rcp
__device__ __forceinline__ float sigmoidf_(float z) {
  return __builtin_amdgcn_rcpf(1.0f + __expf(-z));
}

// ---------------- fused scan (blocks 0..127) + prep (blocks 128..255) ------
// scan block: (b = blk>>5, dgroup = blk&31). tid = chunk*16 + dp.
// Each thread scans 32 t-steps of 2 channels (d0 = dgroup*32 + dp*2).
__global__ __launch_bounds__(1024, 4) void k_scan(
    const float* __restrict__ x,
    const float* __restrict__ fgs, const float* __restrict__ fvs,
    const float* __restrict__ sgs, const float* __restrict__ svs,
    const float* __restrict__ fow, const float* __restrict__ sow,
    const float* __restrict__ mw,  const float* __restrict__ nw,
    unsigned short* __restrict__ xb,
    unsigned short* __restrict__ wcat, unsigned short* __restrict__ w2,
    float* __restrict__ rowsum,
    unsigned short* __restrict__ hcat) {
  if (blockIdx.x >= 128) {                 // ---- prep part (grid-stride) ----
    for (int it = (blockIdx.x - 128) * 1024 + threadIdx.x; it < 1056768;
         it += 131072) {
      if (it < 524288) {
        int i = it * 4;
        const float* src = (i < 1048576) ? (fow + i) : (sow + (i - 1048576));
        f32x4 v = *(const f32x4*)src;
        ushort4v o = { f2b(v.x), f2b(v.y), f2b(v.z), f2b(v.w) };
        *(ushort4v*)&wcat[i] = o;
      } else if (it < 1048576) {
        int i = (it - 524288) * 4;
        int m = i & 2047;
        f32x4 v = *(const f32x4*)&mw[i];
        f32x4 s = *(const f32x4*)&nw[m];
        ushort4v o = { f2b(v.x * s.x), f2b(v.y * s.y), f2b(v.z * s.z), f2b(v.w * s.w) };
        *(ushort4v*)&w2[i] = o;
      } else {
        rowsum[it - 1048576] = 0.f;
      }
    }
    return;
  }
  // ---- scan part ----
  __shared__ f32x2 sPF[64][16], sHF[64][16], sPS[64][16], sHS[64][16];  // 32 KB
  __shared__ f32x2 sCF[64][16], sCS[64][16];                            // 16 KB
  const int tid = threadIdx.x;
  const int chunk = tid >> 4, dp = tid & 15;
  const int b = blockIdx.x >> 5, dg = blockIdx.x & 31;
  const int d0 = dg * 32 + dp * 2;

  float fg0 = 1.f, fg1 = 1.f, fv0 = 1.f, fv1 = 1.f;
  float sg0 = 1.f, sg1 = 1.f, sv0 = 1.f, sv1 = 1.f;
#pragma unroll
  for (int i = 0; i < 5; ++i) {
    f32x2 a = *(const f32x2*)&fgs[i * 1024 + d0]; fg0 *= a.x; fg1 *= a.y;
    f32x2 bq = *(const f32x2*)&fvs[i * 1024 + d0]; fv0 *= bq.x; fv1 *= bq.y;
    f32x2 c = *(const f32x2*)&sgs[i * 1024 + d0]; sg0 *= c.x; sg1 *= c.y;
    f32x2 e = *(const f32x2*)&svs[i * 1024 + d0]; sv0 *= e.x; sv1 *= e.y;
  }
  size_t base = ((size_t)(b * 2048 + chunk * 32)) * 1024 + d0;
  // preload ALL t-steps (independent -> deep pipeline; stores come after)
  f32x2 xv[32];
#pragma unroll
  for (int t = 0; t < 32; ++t)
    xv[t] = *(const f32x2*)&x[base + (size_t)t * 1024];
  float pF0 = 1.f, hF0 = 0.f, pS0 = 1.f, hS0 = 0.f;
  float pF1 = 1.f, hF1 = 0.f, pS1 = 1.f, hS1 = 0.f;
#pragma unroll
  for (int t = 0; t < 32; ++t) {
    *(ushort2v*)&xb[base + (size_t)t * 1024] =
        ushort2v{f2b(xv[t].x), f2b(xv[t].y)};
    float fF0 = sigmoidf_(xv[t].x * fg0 + 0.5f);
    hF0 = fF0 * hF0 + (1.f - fF0) * (xv[t].x * fv0); pF0 *= fF0;
    float fS0 = 0.85f + 0.15f * sigmoidf_(xv[t].x * sg0 + 0.5f);
    hS0 = fS0 * hS0 + (1.f - fS0) * (xv[t].x * sv0); pS0 *= fS0;
    float fF1 = sigmoidf_(xv[t].y * fg1 + 0.5f);
    hF1 = fF1 * hF1 + (1.f - fF1) * (xv[t].y * fv1); pF1 *= fF1;
    float fS1 = 0.85f + 0.15f * sigmoidf_(xv[t].y * sg1 + 0.5f);
    hS1 = fS1 * hS1 + (1.f - fS1) * (xv[t].y * sv1); pS1 *= fS1;
  }
  sPF[chunk][dp] = f32x2{pF0, pF1};
  sHF[chunk][dp] = f32x2{hF0, hF1};
  sPS[chunk][dp] = f32x2{pS0, pS1};
  sHS[chunk][dp] = f32x2{hS0, hS1};
  __syncthreads();

  // carry prefix across chunks, in LDS. threads 0..15: fast, 16..31: slow.
  if (tid < 32) {
    const int dpp = tid & 15;
    if (tid < 16) {
      f32x2 c = {0.f, 0.f};
#pragma unroll
      for (int cn = 0; cn < 64; ++cn) {
        sCF[cn][dpp] = c;
        f32x2 p = sPF[cn][dpp], h = sHF[cn][dpp];
        c.x = h.x + p.x * c.x; c.y = h.y + p.y * c.y;
      }
    } else {
      f32x2 c = {0.f, 0.f};
#pragma unroll
      for (int cn = 0; cn < 64; ++cn) {
        sCS[cn][dpp] = c;
        f32x2 p = sPS[cn][dpp], h = sHS[cn][dpp];
        c.x = h.x + p.x * c.x; c.y = h.y + p.y * c.y;
      }
    }
  }
  __syncthreads();

  // rescan from registers with carry-in -> hcat
  const f32x2 cF = sCF[chunk][dp], cS = sCS[chunk][dp];
  pF0 = 1.f; hF0 = 0.f; pS0 = 1.f; hS0 = 0.f;
  pF1 = 1.f; hF1 = 0.f; pS1 = 1.f; hS1 = 0.f;
#pragma unroll
  for (int t = 0; t < 32; ++t) {
    float fF0 = sigmoidf_(xv[t].x * fg0 + 0.5f);
    hF0 = fF0 * hF0 + (1.f - fF0) * (xv[t].x * fv0); pF0 *= fF0;
    float fS0 = 0.85f + 0.15f * sigmoidf_(xv[t].x * sg0 + 0.5f);
    hS0 = fS0 * hS0 + (1.f - fS0) * (xv[t].x * sv0); pS0 *= fS0;
    float fF1 = sigmoidf_(xv[t].y * fg1 + 0.5f);
    hF1 = fF1 * hF1 + (1.f - fF1) * (xv[t].y * fv1); pF1 *= fF1;
    float fS1 = 0.85f + 0.15f * sigmoidf_(xv[t].y * sg1 + 0.5f);
    hS1 = fS1 * hS1 + (1.f - fS1) * (xv[t].y * sv1); pS1 *= fS1;
    size_t bt = (size_t)(b * 2048 + chunk * 32 + t);
    *(ushort2v*)&hcat[bt * 2048 + d0] =
        ushort2v{f2b(hF0 + pF0 * cF.x), f2b(hF1 + pF1 * cF.y)};
    *(ushort2v*)&hcat[bt * 2048 + 1024 + d0] =
        ushort2v{f2b(hS0 + pS0 * cS.x), f2b(hS1 + pS1 * cS.y)};
  }
}

// ------------------------- bf16 MFMA GEMM, 16x16x32, BK=64, swizzled -------
// C[m,n] = sum_k A[m,k]*B[n,k].  Block tile (2*WM)x(2*WN), 4 waves 2x2, each
// wave WMxWN of 16x16 MFMA tiles, BK=64 (2 sub-steps per barrier pair).
// LDS row stride 64 elts; 16B-chunk slot = chunk ^ (row&7): conflict-free.
// Grid 1D, XCD remap: col=(n>>3)&(2^CB-1); band=(n&7)|((n>>(3+CB))<<3).
// MODE 1: merged = bf16(sigmoid(C)*hcat); rowsum[m] += sum_n v^2 (atomic)
// MODE 2: out = rsqrt(rowsum[m]/2048 + 1e-6) * C
template <int WM, int WN, int MODE, int CB>
__global__ __launch_bounds__(256, 4) void k_gemm(
    const unsigned short* __restrict__ A, const unsigned short* __restrict__ B,
    const int K,
    const unsigned short* __restrict__ hcat, unsigned short* __restrict__ merged,
    float* __restrict__ rowsum, float* __restrict__ out) {
  constexpr int BM = 2 * WM, BN = 2 * WN;
  constexpr int RA = BM / 32, RB = BN / 32;   // cp16 rounds (8 rows each)
  constexpr int AM = WM / 16, BT = WN / 16;
  __shared__ __align__(16) unsigned short sA[BM * 64];
  __shared__ __align__(16) unsigned short sB[BN * 64];
  const int tid = threadIdx.x, wv = tid >> 6, ln = tid & 63;
  const int n_ = blockIdx.x;
  const int col = (n_ >> 3) & ((1 << CB) - 1);
  const int band = (n_ & 7) | ((n_ >> (3 + CB)) << 3);
  const int bm = band * BM, bn = col * BN;

  const int srow = ln >> 3;                       // 0..7 within round
  const int clog = (ln & 7) ^ srow;               // swizzled logical chunk
  const unsigned short* gA[RA]; unsigned short* lA[RA];
  const unsigned short* gB[RB]; unsigned short* lB[RB];
#pragma unroll
  for (int j = 0; j < RA; ++j) {
    const int R0 = wv * (BM / 4) + j * 8;
    gA[j] = A + (size_t)(bm + R0 + srow) * K + clog * 8;
    lA[j] = &sA[R0 * 64 + ln * 8];
  }
#pragma unroll
  for (int j = 0; j < RB; ++j) {
    const int R0 = wv * (BN / 4) + j * 8;
    gB[j] = B + (size_t)(bn + R0 + srow) * K + clog * 8;
    lB[j] = &sB[R0 * 64 + ln * 8];
  }

  const int fr = ln & 15, fq = ln >> 4;           // frag row, chunk base 0..3
  const int wm = (wv >> 1) * WM, wn = (wv & 1) * WN;

  f32x4 acc[AM][BT];
  const f32x4 z4 = {0.f, 0.f, 0.f, 0.f};
#pragma unroll
  for (int i = 0; i < AM; ++i)
#pragma unroll
    for (int j = 0; j < BT; ++j) acc[i][j] = z4;

  for (int k0 = 0; k0 < K; k0 += 64) {
#pragma unroll
    for (int j = 0; j < RA; ++j) cp16(gA[j] + k0, lA[j]);
#pragma unroll
    for (int j = 0; j < RB; ++j) cp16(gB[j] + k0, lB[j]);
    __syncthreads();
#pragma unroll
    for (int sub = 0; sub < 2; ++sub) {
      short8 af[AM], bf[BT];
#pragma unroll
      for (int mi = 0; mi < AM; ++mi) {
        const int row = wm + mi * 16 + fr;
        const int slot = (fq + sub * 4) ^ (row & 7);
        af[mi] = *(const short8*)&sA[row * 64 + slot * 8];
      }
#pragma unroll
      for (int ni = 0; ni < BT; ++ni) {
        const int row = wn + ni * 16 + fr;
        const int slot = (fq + sub * 4) ^ (row & 7);
        bf[ni] = *(const short8*)&sB[row * 64 + slot * 8];
      }
#pragma unroll
      for (int mi = 0; mi < AM; ++mi)
#pragma unroll
        for (int ni = 0; ni < BT; ++ni)
          acc[mi][ni] = __builtin_amdgcn_mfma_f32_16x16x32_bf16(
              af[mi], bf[ni], acc[mi][ni], 0, 0, 0);
    }
    __syncthreads();
  }

  // C/D layout: col = lane&15, row = (lane>>4)*4 + reg   [verified m89/m91]
  const int er0 = fq * 4;
  if (MODE == 1) {
#pragma unroll
    for (int mi = 0; mi < AM; ++mi) {
#pragma unroll
      for (int r = 0; r < 4; ++r) {
        const int m = bm + wm + mi * 16 + er0 + r;
        float s = 0.f;
#pragma unroll
        for (int ni = 0; ni < BT; ++ni) {
          const int n = bn + wn + ni * 16 + fr;
          const size_t idx = (size_t)m * 2048 + n;
          float v = sigmoidf_(acc[mi][ni][r]) * b2f(hcat[idx]);
          merged[idx] = f2b(v);
          s += v * v;
        }
        s += __shfl_xor(s, 1); s += __shfl_xor(s, 2);
        s += __shfl_xor(s, 4); s += __shfl_xor(s, 8);
        if (fr == 0) atomicAdd(&rowsum[m], s);
      }
    }
  } else {
#pragma unroll
    for (int mi = 0; mi < AM; ++mi) {
#pragma unroll
      for (int r = 0; r < 4; ++r) {
        const int m = bm + wm + mi * 16 + er0 + r;
        const float rf = rsqrtf(rowsum[m] * (1.0f / 2048.0f) + 1e-6f);
#pragma unroll
        for (int ni = 0; ni < BT; ++ni) {
          const int n = bn + wn + ni * 16 + fr;
          out[(size_t)m * 1024 + n] = rf * acc[mi][ni][r];
        }
      }
    }
  }
}

// ---------------------------------------------------------------------------
extern "C" void kernel_launch(void* const* d_in, const int* in_sizes, int n_in,
                              void* d_out, int out_size, void* d_ws, size_t ws_size,
                              hipStream_t stream) {
  const float* x   = (const float*)d_in[0];
  const float* fgs = (const float*)d_in[1];
  const float* fvs = (const float*)d_in[2];
  const float* fow = (const float*)d_in[3];
  const float* sgs = (const float*)d_in[4];
  const float* svs = (const float*)d_in[5];
  const float* sow = (const float*)d_in[6];
  const float* mw  = (const float*)d_in[7];
  const float* nw  = (const float*)d_in[8];
  float* out = (float*)d_out;

  char* ws = (char*)d_ws;
  float* rowsum = (float*)(ws + 0);                         // 32 KB
  unsigned short* xb   = (unsigned short*)(ws + 32768);     // 16 MB
  unsigned short* wcat = (unsigned short*)(ws + 16809984);  // 4 MB
  unsigned short* w2   = (unsigned short*)(ws + 21004288);  // 4 MB
  unsigned short* hcat = (unsigned short*)(ws + 25198592);  // 32 MB
  unsigned short* mg   = (unsigned short*)(ws + 58753024);  // 32 MB (end ~92MB)

  // fused scan (blocks 0..127, 1024 thr: 64 chunks x 16 d-pairs) +
  // weight prep (blocks 128..255, grid-stride)
  k_scan<<<256, 1024, 0, stream>>>(x, fgs, fvs, sgs, svs, fow, sow, mw, nw,
                                   xb, wcat, w2, rowsum, hcat);
  // GEMM1: M=8192, N=2048, K=1024; tile 128x128; 64 bands x 16 cols
  k_gemm<64, 64, 1, 4><<<1024, 256, 0, stream>>>(
      xb, wcat, 1024, hcat, mg, rowsum, nullptr);
  // GEMM2: M=8192, N=1024, K=2048; tile 64x128; 128 bands x 8 cols
  k_gemm<32, 64, 2, 3><<<1024, 256, 0, stream>>>(
      mg, w2, 2048, nullptr, nullptr, rowsum, out);
}